// Round 2
// baseline (268.208 us; speedup 1.0000x reference)
//
#include <hip/hip_runtime.h>
#include <math.h>

// Problem constants (from reference): B=32, C=2, L=262144, K=4
#define B_N 32
#define C_N 2
#define L_N 262144
#define K_N 4
#define NSEQ (B_N * C_N)          // 64 independent sequences
#define CHUNK 32                  // samples per chunk-thread
#define NCHUNK (L_N / CHUNK)      // 8192 chunks per sequence
#define GRP 8                     // chunks per scan thread
#define NGRP (NCHUNK / GRP)       // 1024 groups per sequence
#define NLVL 10                   // log2(NGRP) scan levels
// d_ws float layout: [coef 32*20][A32 32*64][mats 32*10*64]  (~92.7 KB)
#define WS_COEF 0
#define WS_A32  (B_N * 20)
#define WS_MATS (WS_A32 + B_N * 64)

// ---------------------------------------------------------------------------
// K1: per-batch coefficient prep + transition-matrix powers (fp64).
// 32 blocks (one per b) x 64 threads. Lane (i,j) owns element [i][j] of the
// 8x8 cascade transition matrix during repeated squaring.
// ---------------------------------------------------------------------------
__global__ __launch_bounds__(64) void svf_prep(
    const float* __restrict__ twoR, const float* __restrict__ Graw,
    const float* __restrict__ c_hp, const float* __restrict__ c_bp,
    const float* __restrict__ c_lp, float* __restrict__ ws)
{
    const int b = blockIdx.x;
    const int t = threadIdx.x;
    __shared__ double cf[K_N][5];   // b0,b1,b2,a1,a2 (normalized, a0==1)
    __shared__ double M[8][8];

    if (t < K_N) {
        const int k = t;
        double g  = (double)Graw[b * K_N + k];
        double tr = (double)twoR[b * K_N + k];
        double hp = (double)c_hp[b * K_N + k];
        double bp = (double)c_bp[b * K_N + k];
        double lp = (double)c_lp[b * K_N + k];
        double sg = 1.0 / (1.0 + exp(-g));
        double G  = tan(1.5707963267948966 * sg);
        double R  = log1p(exp(tr)) * 1.4426950408889634 + 0.01; // softplus/ln2 + .01
        double G2 = G * G;
        double b0 = hp + bp * G + lp * G2;
        double b1 = -2.0 * hp + 2.0 * lp * G2;
        double b2 = hp - bp * G + lp * G2;
        double a0 = 1.0 + G2 + R * G;
        double a1 = 2.0 * G2 - 2.0;
        double a2 = 1.0 + G2 - R * G;
        cf[k][0] = b0 / a0; cf[k][1] = b1 / a0; cf[k][2] = b2 / a0;
        cf[k][3] = a1 / a0; cf[k][4] = a2 / a0;
    }
    __syncthreads();

    if (t < 20) ws[WS_COEF + b * 20 + t] = (float)cf[t / 5][t % 5];

    // Build A columns: one cascade step from s = e_t, x = 0.
    if (t < 8) {
        double s[8];
        #pragma unroll
        for (int i = 0; i < 8; ++i) s[i] = (i == t) ? 1.0 : 0.0;
        double in = 0.0;
        #pragma unroll
        for (int k = 0; k < K_N; ++k) {
            double y   = cf[k][0] * in + s[2 * k];
            double s1n = cf[k][1] * in - cf[k][3] * y + s[2 * k + 1];
            double s2n = cf[k][2] * in - cf[k][4] * y;
            s[2 * k] = s1n; s[2 * k + 1] = s2n; in = y;
        }
        #pragma unroll
        for (int i = 0; i < 8; ++i) M[i][t] = s[i];
    }
    __syncthreads();

    // Repeated squaring: after p squarings M = A^(2^p).
    // Store A^32 (p=5) and A^(256*2^l) = A^(2^(8+l)), l=0..9.
    const int i = t >> 3, j = t & 7;
    for (int p = 1; p <= 17; ++p) {
        double acc = 0.0;
        #pragma unroll
        for (int k = 0; k < 8; ++k) acc += M[i][k] * M[k][j];
        __syncthreads();          // everyone finished reading old M
        M[i][j] = acc;
        __syncthreads();          // writes visible before next round's reads
        if (p == 5) ws[WS_A32 + b * 64 + t] = (float)acc;
        if (p >= 8) ws[WS_MATS + (b * NLVL + (p - 8)) * 64 + t] = (float)acc;
    }
}

// ---------------------------------------------------------------------------
// Fused 4-biquad cascade step (normalized coefficients). 20 VALU ops/sample.
// ---------------------------------------------------------------------------
__device__ __forceinline__ float cascade_step(const float cf[20], float s[8], float in)
{
    #pragma unroll
    for (int k = 0; k < K_N; ++k) {
        float y  = fmaf(cf[k * 5 + 0], in, s[2 * k]);
        float t1 = fmaf(cf[k * 5 + 1], in, s[2 * k + 1]);
        float n1 = fmaf(-cf[k * 5 + 3], y, t1);
        float n2 = fmaf(-cf[k * 5 + 4], y, cf[k * 5 + 2] * in);
        s[2 * k] = n1; s[2 * k + 1] = n2;
        in = y;
    }
    return in;
}

// ---------------------------------------------------------------------------
// K2: zero-state pass. One thread per 32-sample chunk; writes final 8-state
// f into this thread's OWN slice of d_out (offset +8 floats) — race-free.
// 524288 threads -> 32 waves/CU (full occupancy).
// ---------------------------------------------------------------------------
__global__ __launch_bounds__(256) void svf_pass1(
    const float* __restrict__ x, const float* __restrict__ ws,
    float* __restrict__ out)
{
    const int g   = blockIdx.x * blockDim.x + threadIdx.x;
    const int seq = g >> 13;              // g / NCHUNK
    const int ci  = g & (NCHUNK - 1);
    const int b   = seq >> 1;             // seq / C
    float cf[20];
    #pragma unroll
    for (int q = 0; q < 20; ++q) cf[q] = ws[WS_COEF + b * 20 + q];

    const size_t base = (size_t)seq * L_N + (size_t)ci * CHUNK;
    const float4* xp = (const float4*)(x + base);
    float s[8] = {0, 0, 0, 0, 0, 0, 0, 0};

    #pragma unroll
    for (int t4 = 0; t4 < CHUNK / 4; ++t4) {
        float4 v = xp[t4];
        (void)cascade_step(cf, s, v.x);
        (void)cascade_step(cf, s, v.y);
        (void)cascade_step(cf, s, v.z);
        (void)cascade_step(cf, s, v.w);
    }
    float4* fo = (float4*)(out + base + 8);
    fo[0] = make_float4(s[0], s[1], s[2], s[3]);
    fo[1] = make_float4(s[4], s[5], s[6], s[7]);
}

// ---------------------------------------------------------------------------
// K3: per-sequence scan. Thread i owns GRP=8 consecutive chunks:
//  (a) serially compose their zero-state maps via A^32  -> group vector t
//  (b) Kogge-Stone over 1024 groups with A^(256*2^l)
//  (c) redistribute: walk A^32 forward through the group, writing each
//      chunk's initial state into out[chunk_base + 0..8).
// ---------------------------------------------------------------------------
__global__ __launch_bounds__(1024) void svf_scan(
    const float* __restrict__ ws, float* __restrict__ out)
{
    const int seq = blockIdx.x;
    const int i   = threadIdx.x;
    const int b   = seq >> 1;
    __shared__ float Pm[NLVL][64];
    __shared__ float A32[64];
    __shared__ float tb[NGRP][9];         // pad 8->9 to break bank conflicts

    for (int q = threadIdx.x; q < NLVL * 64; q += blockDim.x)
        Pm[q >> 6][q & 63] = ws[WS_MATS + b * NLVL * 64 + q];
    if (threadIdx.x < 64) A32[threadIdx.x] = ws[WS_A32 + b * 64 + threadIdx.x];

    // Load the 8 per-chunk zero-state vectors f[j].
    const size_t gbase = (size_t)seq * L_N + (size_t)i * (GRP * CHUNK);
    float f[GRP][8];
    #pragma unroll
    for (int j = 0; j < GRP; ++j) {
        const float4* fp = (const float4*)(out + gbase + (size_t)j * CHUNK + 8);
        float4 a = fp[0], bv = fp[1];
        f[j][0] = a.x; f[j][1] = a.y; f[j][2] = a.z; f[j][3] = a.w;
        f[j][4] = bv.x; f[j][5] = bv.y; f[j][6] = bv.z; f[j][7] = bv.w;
    }
    __syncthreads();    // Pm/A32 loaded

    // (a) group zero-state vector: t = f0 folded through A^32, +f1, ...
    float t[8];
    #pragma unroll
    for (int r = 0; r < 8; ++r) t[r] = f[0][r];
    #pragma unroll
    for (int j = 1; j < GRP; ++j) {
        float nt[8];
        #pragma unroll
        for (int r = 0; r < 8; ++r) {
            float acc = f[j][r];
            #pragma unroll
            for (int c = 0; c < 8; ++c) acc = fmaf(A32[r * 8 + c], t[c], acc);
            nt[r] = acc;
        }
        #pragma unroll
        for (int r = 0; r < 8; ++r) t[r] = nt[r];
    }

    // (b) Kogge-Stone over groups
    for (int l = 0; l < NLVL; ++l) {
        const int d = 1 << l;
        #pragma unroll
        for (int q = 0; q < 8; ++q) tb[i][q] = t[q];
        __syncthreads();
        float prev[8];
        const bool have = (i >= d);
        if (have) {
            #pragma unroll
            for (int q = 0; q < 8; ++q) prev[q] = tb[i - d][q];
        }
        __syncthreads();
        if (have) {
            #pragma unroll
            for (int r = 0; r < 8; ++r) {
                float acc = t[r];
                #pragma unroll
                for (int c = 0; c < 8; ++c)
                    acc = fmaf(Pm[l][r * 8 + c], prev[c], acc);
                t[r] = acc;
            }
        }
    }

    #pragma unroll
    for (int q = 0; q < 8; ++q) tb[i][q] = t[q];
    __syncthreads();

    // (c) group initial state, then walk forward through the 8 chunks
    float u[8];
    if (i == 0) {
        #pragma unroll
        for (int q = 0; q < 8; ++q) u[q] = 0.0f;
    } else {
        #pragma unroll
        for (int q = 0; q < 8; ++q) u[q] = tb[i - 1][q];
    }
    #pragma unroll
    for (int j = 0; j < GRP; ++j) {
        float4* so = (float4*)(out + gbase + (size_t)j * CHUNK);
        so[0] = make_float4(u[0], u[1], u[2], u[3]);
        so[1] = make_float4(u[4], u[5], u[6], u[7]);
        if (j < GRP - 1) {
            float nu[8];
            #pragma unroll
            for (int r = 0; r < 8; ++r) {
                float acc = f[j][r];
                #pragma unroll
                for (int c = 0; c < 8; ++c) acc = fmaf(A32[r * 8 + c], u[c], acc);
                nu[r] = acc;
            }
            #pragma unroll
            for (int r = 0; r < 8; ++r) u[r] = nu[r];
        }
    }
}

// ---------------------------------------------------------------------------
// K4: final pass. Read own chunk's initial state (written by K3 into this
// thread's own output slice), rerun the cascade, write y.
// ---------------------------------------------------------------------------
__global__ __launch_bounds__(256) void svf_pass2(
    const float* __restrict__ x, const float* __restrict__ ws,
    float* __restrict__ out)
{
    const int g   = blockIdx.x * blockDim.x + threadIdx.x;
    const int seq = g >> 13;
    const int ci  = g & (NCHUNK - 1);
    const int b   = seq >> 1;
    float cf[20];
    #pragma unroll
    for (int q = 0; q < 20; ++q) cf[q] = ws[WS_COEF + b * 20 + q];

    const size_t base = (size_t)seq * L_N + (size_t)ci * CHUNK;
    const float4* sp = (const float4*)(out + base);
    float4 s0 = sp[0], s1v = sp[1];
    float s[8] = {s0.x, s0.y, s0.z, s0.w, s1v.x, s1v.y, s1v.z, s1v.w};

    const float4* xp = (const float4*)(x + base);
    float4* yp = (float4*)(out + base);
    #pragma unroll
    for (int t4 = 0; t4 < CHUNK / 4; ++t4) {
        float4 v = xp[t4];
        float y0 = cascade_step(cf, s, v.x);
        float y1 = cascade_step(cf, s, v.y);
        float y2 = cascade_step(cf, s, v.z);
        float y3 = cascade_step(cf, s, v.w);
        yp[t4] = make_float4(y0, y1, y2, y3);
    }
}

// ---------------------------------------------------------------------------
extern "C" void kernel_launch(void* const* d_in, const int* in_sizes, int n_in,
                              void* d_out, int out_size, void* d_ws, size_t ws_size,
                              hipStream_t stream)
{
    (void)in_sizes; (void)n_in; (void)out_size; (void)ws_size;
    const float* x    = (const float*)d_in[0];
    const float* twoR = (const float*)d_in[1];
    const float* G    = (const float*)d_in[2];
    const float* chp  = (const float*)d_in[3];
    const float* cbp  = (const float*)d_in[4];
    const float* clp  = (const float*)d_in[5];
    float* out = (float*)d_out;
    float* ws  = (float*)d_ws;

    svf_prep <<<B_N, 64, 0, stream>>>(twoR, G, chp, cbp, clp, ws);
    svf_pass1<<<NSEQ * NCHUNK / 256, 256, 0, stream>>>(x, ws, out);
    svf_scan <<<NSEQ, NCHUNK / GRP, 0, stream>>>(ws, out);
    svf_pass2<<<NSEQ * NCHUNK / 256, 256, 0, stream>>>(x, ws, out);
}

// Round 3
// 202.022 us; speedup vs baseline: 1.3276x; 1.3276x over previous
//
#include <hip/hip_runtime.h>
#include <math.h>

// Problem constants (from reference): B=32, C=2, L=262144, K=4
#define B_N 32
#define C_N 2
#define L_N 262144
#define K_N 4
#define NSEQ (B_N * C_N)            // 64 independent sequences
#define CHUNK 64                    // samples per chunk-thread
#define THREADS 256                 // threads per pass block
#define BLKSAMP (CHUNK * THREADS)   // 16384 samples per block
#define NBLK_SEQ (L_N / BLKSAMP)    // 16 blocks per sequence
#define NBLK_TOT (NSEQ * NBLK_SEQ)  // 1024 pass blocks
#define NLVL 8                      // log2(THREADS) intra-block scan levels

// d_ws float layout:
//   [coef  : 32*20            =   640]
//   [PL    : 32*8*64          = 16384]  A^(64*2^l), l=0..7, per b
//   [PBLK  : 32*64            =  2048]  A^16384 per b
//   [AGG   : 1024*8           =  8192]  block zero-state aggregates
//   [SBLK  : 1024*8           =  8192]  block initial states
#define WS_COEF 0
#define WS_PL   (B_N * 20)
#define WS_PBLK (WS_PL + B_N * 8 * 64)
#define WS_AGG  (WS_PBLK + B_N * 64)
#define WS_SBLK (WS_AGG + NBLK_TOT * 8)

// ---------------------------------------------------------------------------
// K1: per-batch coefficient prep + transition-matrix powers (fp64).
// 32 blocks (one per b) x 64 threads. Lane (i,j) owns element [i][j] of the
// 8x8 cascade transition matrix during repeated squaring.
// ---------------------------------------------------------------------------
__global__ __launch_bounds__(64) void svf_prep(
    const float* __restrict__ twoR, const float* __restrict__ Graw,
    const float* __restrict__ c_hp, const float* __restrict__ c_bp,
    const float* __restrict__ c_lp, float* __restrict__ ws)
{
    const int b = blockIdx.x;
    const int t = threadIdx.x;
    __shared__ double cf[K_N][5];   // b0,b1,b2,a1,a2 (normalized, a0==1)
    __shared__ double M[8][8];

    if (t < K_N) {
        const int k = t;
        double g  = (double)Graw[b * K_N + k];
        double tr = (double)twoR[b * K_N + k];
        double hp = (double)c_hp[b * K_N + k];
        double bp = (double)c_bp[b * K_N + k];
        double lp = (double)c_lp[b * K_N + k];
        double sg = 1.0 / (1.0 + exp(-g));
        double G  = tan(1.5707963267948966 * sg);
        double R  = log1p(exp(tr)) * 1.4426950408889634 + 0.01; // softplus/ln2 + .01
        double G2 = G * G;
        double b0 = hp + bp * G + lp * G2;
        double b1 = -2.0 * hp + 2.0 * lp * G2;
        double b2 = hp - bp * G + lp * G2;
        double a0 = 1.0 + G2 + R * G;
        double a1 = 2.0 * G2 - 2.0;
        double a2 = 1.0 + G2 - R * G;
        cf[k][0] = b0 / a0; cf[k][1] = b1 / a0; cf[k][2] = b2 / a0;
        cf[k][3] = a1 / a0; cf[k][4] = a2 / a0;
    }
    __syncthreads();

    if (t < 20) ws[WS_COEF + b * 20 + t] = (float)cf[t / 5][t % 5];

    // Build A columns: one cascade step from s = e_t, x = 0.
    if (t < 8) {
        double s[8];
        #pragma unroll
        for (int i = 0; i < 8; ++i) s[i] = (i == t) ? 1.0 : 0.0;
        double in = 0.0;
        #pragma unroll
        for (int k = 0; k < K_N; ++k) {
            double y   = cf[k][0] * in + s[2 * k];
            double s1n = cf[k][1] * in - cf[k][3] * y + s[2 * k + 1];
            double s2n = cf[k][2] * in - cf[k][4] * y;
            s[2 * k] = s1n; s[2 * k + 1] = s2n; in = y;
        }
        #pragma unroll
        for (int i = 0; i < 8; ++i) M[i][t] = s[i];
    }
    __syncthreads();

    // Repeated squaring: after p squarings M = A^(2^p).
    // Store A^(2^(6+l)) l=0..7 (intra-block scan + bit-decomp) and A^(2^14).
    const int i = t >> 3, j = t & 7;
    for (int p = 1; p <= 14; ++p) {
        double acc = 0.0;
        #pragma unroll
        for (int k = 0; k < 8; ++k) acc += M[i][k] * M[k][j];
        __syncthreads();          // everyone finished reading old M
        M[i][j] = acc;
        __syncthreads();          // writes visible before next round's reads
        if (p >= 6 && p <= 13) ws[WS_PL + (b * 8 + (p - 6)) * 64 + t] = (float)acc;
        if (p == 14)           ws[WS_PBLK + b * 64 + t] = (float)acc;
    }
}

// ---------------------------------------------------------------------------
// Fused 4-biquad cascade step (normalized coefficients). 20 VALU ops/sample.
// ---------------------------------------------------------------------------
__device__ __forceinline__ float cascade_step(const float cf[20], float s[8], float in)
{
    #pragma unroll
    for (int k = 0; k < K_N; ++k) {
        float y  = fmaf(cf[k * 5 + 0], in, s[2 * k]);
        float t1 = fmaf(cf[k * 5 + 1], in, s[2 * k + 1]);
        float n1 = fmaf(-cf[k * 5 + 3], y, t1);
        float n2 = fmaf(-cf[k * 5 + 4], y, cf[k * 5 + 2] * in);
        s[2 * k] = n1; s[2 * k + 1] = n2;
        in = y;
    }
    return in;
}

// ---------------------------------------------------------------------------
// K2: zero-state pass + intra-block scan.
// Block = 256 threads = 16384 samples. Thread = 64-sample chunk.
// Writes: per-thread EXCLUSIVE intra-block prefix -> own d_out slice;
//         block zero-state aggregate (thread 255) -> ws[AGG].
// ---------------------------------------------------------------------------
__global__ __launch_bounds__(THREADS) void svf_pass1(
    const float* __restrict__ x, const float* __restrict__ ws,
    float* __restrict__ out)
{
    const int seq = blockIdx.x >> 4;          // / NBLK_SEQ
    const int blk = blockIdx.x & (NBLK_SEQ - 1);
    const int tid = threadIdx.x;
    const int b   = seq >> 1;

    __shared__ float Pm[NLVL][64];
    __shared__ float tb[THREADS][9];          // pad 8->9: no bank conflicts

    for (int q = tid; q < NLVL * 64; q += THREADS)
        Pm[q >> 6][q & 63] = ws[WS_PL + b * 8 * 64 + q];

    float cf[20];
    #pragma unroll
    for (int q = 0; q < 20; ++q) cf[q] = ws[WS_COEF + b * 20 + q];

    const size_t base = (size_t)seq * L_N + (size_t)blk * BLKSAMP + (size_t)tid * CHUNK;
    const float4* xp = (const float4*)(x + base);
    float t[8] = {0, 0, 0, 0, 0, 0, 0, 0};
    #pragma unroll
    for (int t4 = 0; t4 < CHUNK / 4; ++t4) {
        float4 v = xp[t4];
        (void)cascade_step(cf, t, v.x);
        (void)cascade_step(cf, t, v.y);
        (void)cascade_step(cf, t, v.z);
        (void)cascade_step(cf, t, v.w);
    }
    __syncthreads();                           // Pm loaded

    // Kogge-Stone over 256 chunk maps (uniform matrix per level).
    for (int l = 0; l < NLVL; ++l) {
        const int d = 1 << l;
        #pragma unroll
        for (int q = 0; q < 8; ++q) tb[tid][q] = t[q];
        __syncthreads();
        float prev[8];
        const bool have = (tid >= d);
        if (have) {
            #pragma unroll
            for (int q = 0; q < 8; ++q) prev[q] = tb[tid - d][q];
        }
        __syncthreads();
        if (have) {
            #pragma unroll
            for (int r = 0; r < 8; ++r) {
                float acc = t[r];
                #pragma unroll
                for (int c = 0; c < 8; ++c)
                    acc = fmaf(Pm[l][r * 8 + c], prev[c], acc);
                t[r] = acc;
            }
        }
    }

    #pragma unroll
    for (int q = 0; q < 8; ++q) tb[tid][q] = t[q];
    __syncthreads();

    // exclusive prefix -> own output slice
    float e[8];
    if (tid == 0) {
        #pragma unroll
        for (int q = 0; q < 8; ++q) e[q] = 0.0f;
    } else {
        #pragma unroll
        for (int q = 0; q < 8; ++q) e[q] = tb[tid - 1][q];
    }
    float4* eo = (float4*)(out + base);
    eo[0] = make_float4(e[0], e[1], e[2], e[3]);
    eo[1] = make_float4(e[4], e[5], e[6], e[7]);

    if (tid == THREADS - 1) {
        float* agg = (float*)ws + WS_AGG + (size_t)blockIdx.x * 8;  // cast-away-const ok: ws is d_ws
        #pragma unroll
        for (int q = 0; q < 8; ++q) agg[q] = t[q];
    }
}

// ---------------------------------------------------------------------------
// K3: inter-block scan. One wave; lane = sequence. Serial fold of 16 block
// aggregates with P = A^16384; writes exclusive prefixes (block init states).
// ---------------------------------------------------------------------------
__global__ __launch_bounds__(64) void svf_scanb(float* __restrict__ ws)
{
    const int seq = threadIdx.x;
    const int b   = seq >> 1;
    float P[64];
    #pragma unroll
    for (int q = 0; q < 64; ++q) P[q] = ws[WS_PBLK + b * 64 + q];

    const float* agg = ws + WS_AGG + (size_t)seq * NBLK_SEQ * 8;
    float* sb        = ws + WS_SBLK + (size_t)seq * NBLK_SEQ * 8;

    float t[8] = {0, 0, 0, 0, 0, 0, 0, 0};
    float f[8];
    #pragma unroll
    for (int q = 0; q < 8; ++q) f[q] = agg[q];          // f_0

    for (int j = 0; j < NBLK_SEQ; ++j) {
        float fn[8];
        if (j + 1 < NBLK_SEQ) {
            #pragma unroll
            for (int q = 0; q < 8; ++q) fn[q] = agg[(j + 1) * 8 + q];  // prefetch
        }
        #pragma unroll
        for (int q = 0; q < 8; ++q) sb[j * 8 + q] = t[q];              // exclusive
        float nt[8];
        #pragma unroll
        for (int r = 0; r < 8; ++r) {
            float acc = f[r];
            #pragma unroll
            for (int c = 0; c < 8; ++c) acc = fmaf(P[r * 8 + c], t[c], acc);
            nt[r] = acc;
        }
        #pragma unroll
        for (int q = 0; q < 8; ++q) { t[q] = nt[q]; f[q] = fn[q]; }
    }
}

// ---------------------------------------------------------------------------
// K4: final pass. Thread init state = stored exclusive prefix
//                                   + A^(64*tid) * S_blk  (commuting bit-decomp,
//                                     no scan, no sync). Then cascade, write y.
// ---------------------------------------------------------------------------
__global__ __launch_bounds__(THREADS) void svf_pass2(
    const float* __restrict__ x, const float* __restrict__ ws,
    float* __restrict__ out)
{
    const int seq = blockIdx.x >> 4;
    const int blk = blockIdx.x & (NBLK_SEQ - 1);
    const int tid = threadIdx.x;
    const int b   = seq >> 1;

    __shared__ float Pm[NLVL][64];
    for (int q = tid; q < NLVL * 64; q += THREADS)
        Pm[q >> 6][q & 63] = ws[WS_PL + b * 8 * 64 + q];

    float cf[20];
    #pragma unroll
    for (int q = 0; q < 20; ++q) cf[q] = ws[WS_COEF + b * 20 + q];

    // block initial state (same address for all threads -> cached/broadcast)
    const float* sbp = ws + WS_SBLK + (size_t)blockIdx.x * 8;
    float v[8];
    #pragma unroll
    for (int q = 0; q < 8; ++q) v[q] = sbp[q];
    __syncthreads();                           // Pm loaded

    // v = A^(CHUNK*tid) * S_blk via commuting power-of-two factors
    #pragma unroll
    for (int l = 0; l < NLVL; ++l) {
        if ((tid >> l) & 1) {
            float nv[8];
            #pragma unroll
            for (int r = 0; r < 8; ++r) {
                float acc = 0.0f;
                #pragma unroll
                for (int c = 0; c < 8; ++c)
                    acc = fmaf(Pm[l][r * 8 + c], v[c], acc);
                nv[r] = acc;
            }
            #pragma unroll
            for (int q = 0; q < 8; ++q) v[q] = nv[q];
        }
    }

    const size_t base = (size_t)seq * L_N + (size_t)blk * BLKSAMP + (size_t)tid * CHUNK;
    const float4* sp = (const float4*)(out + base);    // own slice: excl prefix
    float4 e0 = sp[0], e1 = sp[1];
    float s[8] = {e0.x + v[0], e0.y + v[1], e0.z + v[2], e0.w + v[3],
                  e1.x + v[4], e1.y + v[5], e1.z + v[6], e1.w + v[7]};

    const float4* xp = (const float4*)(x + base);
    float4* yp = (float4*)(out + base);
    #pragma unroll
    for (int t4 = 0; t4 < CHUNK / 4; ++t4) {
        float4 xv = xp[t4];
        float y0 = cascade_step(cf, s, xv.x);
        float y1 = cascade_step(cf, s, xv.y);
        float y2 = cascade_step(cf, s, xv.z);
        float y3 = cascade_step(cf, s, xv.w);
        yp[t4] = make_float4(y0, y1, y2, y3);
    }
}

// ---------------------------------------------------------------------------
extern "C" void kernel_launch(void* const* d_in, const int* in_sizes, int n_in,
                              void* d_out, int out_size, void* d_ws, size_t ws_size,
                              hipStream_t stream)
{
    (void)in_sizes; (void)n_in; (void)out_size; (void)ws_size;
    const float* x    = (const float*)d_in[0];
    const float* twoR = (const float*)d_in[1];
    const float* G    = (const float*)d_in[2];
    const float* chp  = (const float*)d_in[3];
    const float* cbp  = (const float*)d_in[4];
    const float* clp  = (const float*)d_in[5];
    float* out = (float*)d_out;
    float* ws  = (float*)d_ws;

    svf_prep <<<B_N, 64, 0, stream>>>(twoR, G, chp, cbp, clp, ws);
    svf_pass1<<<NBLK_TOT, THREADS, 0, stream>>>(x, ws, out);
    svf_scanb<<<1, 64, 0, stream>>>(ws);
    svf_pass2<<<NBLK_TOT, THREADS, 0, stream>>>(x, ws, out);
}

// Round 4
// 172.618 us; speedup vs baseline: 1.5538x; 1.1703x over previous
//
#include <hip/hip_runtime.h>
#include <math.h>

// Problem constants (from reference): B=32, C=2, L=262144, K=4
#define B_N 32
#define C_N 2
#define L_N 262144
#define K_N 4
#define NSEQ (B_N * C_N)            // 64 independent sequences
#define CHUNK 64                    // samples per chunk-thread
#define THREADS 128                 // threads per pass block
#define BLKSAMP (CHUNK * THREADS)   // 8192 samples per block
#define NBLK_SEQ (L_N / BLKSAMP)    // 32 blocks per sequence
#define NBLK_TOT (NSEQ * NBLK_SEQ)  // 2048 pass blocks
#define NLVL 7                      // log2(THREADS): scan levels / bit-decomp bits
#define ROWP (CHUNK + 1)            // padded LDS row stride (bank-conflict-free)

// d_ws float layout (total 33408 floats = 133.6 KB):
//   [coef : 32*20   =   640]
//   [PL   : 32*7*64 = 14336]  A^(64*2^l), l=0..6, per b
//   [PBLK : 32*64   =  2048]  A^8192 per b
//   [AGG  : 2048*8  = 16384]  block aggregates -> (scanb, in place) block init states
#define WS_COEF 0
#define WS_PL   (B_N * 20)
#define WS_PBLK (WS_PL + B_N * NLVL * 64)
#define WS_AGG  (WS_PBLK + B_N * 64)

// ---------------------------------------------------------------------------
// K1: per-batch coefficient prep + transition-matrix powers (fp64).
// ---------------------------------------------------------------------------
__global__ __launch_bounds__(64) void svf_prep(
    const float* __restrict__ twoR, const float* __restrict__ Graw,
    const float* __restrict__ c_hp, const float* __restrict__ c_bp,
    const float* __restrict__ c_lp, float* __restrict__ ws)
{
    const int b = blockIdx.x;
    const int t = threadIdx.x;
    __shared__ double cf[K_N][5];   // b0,b1,b2,a1,a2 (normalized, a0==1)
    __shared__ double M[8][8];

    if (t < K_N) {
        const int k = t;
        double g  = (double)Graw[b * K_N + k];
        double tr = (double)twoR[b * K_N + k];
        double hp = (double)c_hp[b * K_N + k];
        double bp = (double)c_bp[b * K_N + k];
        double lp = (double)c_lp[b * K_N + k];
        double sg = 1.0 / (1.0 + exp(-g));
        double G  = tan(1.5707963267948966 * sg);
        double R  = log1p(exp(tr)) * 1.4426950408889634 + 0.01; // softplus/ln2 + .01
        double G2 = G * G;
        double b0 = hp + bp * G + lp * G2;
        double b1 = -2.0 * hp + 2.0 * lp * G2;
        double b2 = hp - bp * G + lp * G2;
        double a0 = 1.0 + G2 + R * G;
        double a1 = 2.0 * G2 - 2.0;
        double a2 = 1.0 + G2 - R * G;
        cf[k][0] = b0 / a0; cf[k][1] = b1 / a0; cf[k][2] = b2 / a0;
        cf[k][3] = a1 / a0; cf[k][4] = a2 / a0;
    }
    __syncthreads();

    if (t < 20) ws[WS_COEF + b * 20 + t] = (float)cf[t / 5][t % 5];

    // Build A columns: one cascade step from s = e_t, x = 0.
    if (t < 8) {
        double s[8];
        #pragma unroll
        for (int i = 0; i < 8; ++i) s[i] = (i == t) ? 1.0 : 0.0;
        double in = 0.0;
        #pragma unroll
        for (int k = 0; k < K_N; ++k) {
            double y   = cf[k][0] * in + s[2 * k];
            double s1n = cf[k][1] * in - cf[k][3] * y + s[2 * k + 1];
            double s2n = cf[k][2] * in - cf[k][4] * y;
            s[2 * k] = s1n; s[2 * k + 1] = s2n; in = y;
        }
        #pragma unroll
        for (int i = 0; i < 8; ++i) M[i][t] = s[i];
    }
    __syncthreads();

    // Repeated squaring: after p squarings M = A^(2^p).
    // Store A^(2^(6+l)) l=0..6 (scan + bit-decomp) and A^(2^13) (block map).
    const int i = t >> 3, j = t & 7;
    for (int p = 1; p <= 13; ++p) {
        double acc = 0.0;
        #pragma unroll
        for (int k = 0; k < 8; ++k) acc += M[i][k] * M[k][j];
        __syncthreads();
        M[i][j] = acc;
        __syncthreads();
        if (p >= 6 && p <= 12) ws[WS_PL + (b * NLVL + (p - 6)) * 64 + t] = (float)acc;
        if (p == 13)           ws[WS_PBLK + b * 64 + t] = (float)acc;
    }
}

// ---------------------------------------------------------------------------
// Fused 4-biquad cascade step (normalized coefficients). 20 VALU ops/sample.
// ---------------------------------------------------------------------------
__device__ __forceinline__ float cascade_step(const float cf[20], float s[8], float in)
{
    #pragma unroll
    for (int k = 0; k < K_N; ++k) {
        float y  = fmaf(cf[k * 5 + 0], in, s[2 * k]);
        float t1 = fmaf(cf[k * 5 + 1], in, s[2 * k + 1]);
        float n1 = fmaf(-cf[k * 5 + 3], y, t1);
        float n2 = fmaf(-cf[k * 5 + 4], y, cf[k * 5 + 2] * in);
        s[2 * k] = n1; s[2 * k + 1] = n2;
        in = y;
    }
    return in;
}

// Coalesced tile load: global x[base..base+8192) -> LDS rows [tid][ROWP].
__device__ __forceinline__ void load_tile(const float* __restrict__ xg,
                                          float* __restrict__ xt, int tid)
{
    #pragma unroll
    for (int k = 0; k < BLKSAMP / 4 / THREADS; ++k) {
        const int g0 = (tid + k * THREADS) * 4;         // linear float idx
        float4 v = ((const float4*)xg)[tid + k * THREADS];
        const int a = (g0 >> 6) * ROWP + (g0 & 63);
        xt[a] = v.x; xt[a + 1] = v.y; xt[a + 2] = v.z; xt[a + 3] = v.w;
    }
}

// ---------------------------------------------------------------------------
// K2: zero-state pass + intra-block scan.
// Writes: per-thread EXCLUSIVE prefix -> compact coalesced region at the head
// of the block's own output range; block aggregate -> ws[AGG].
// ---------------------------------------------------------------------------
__global__ __launch_bounds__(THREADS) void svf_pass1(
    const float* __restrict__ x, const float* __restrict__ ws,
    float* __restrict__ out)
{
    const int seq = blockIdx.x >> 5;          // / NBLK_SEQ
    const int blk = blockIdx.x & (NBLK_SEQ - 1);
    const int tid = threadIdx.x;
    const int b   = seq >> 1;

    __shared__ float xt[THREADS * ROWP];      // 33.3 KB
    __shared__ float Pm[NLVL][64];
    __shared__ float tb[THREADS][9];

    for (int q = tid; q < NLVL * 64; q += THREADS)
        Pm[q >> 6][q & 63] = ws[WS_PL + b * NLVL * 64 + q];

    float cf[20];
    #pragma unroll
    for (int q = 0; q < 20; ++q) cf[q] = ws[WS_COEF + b * 20 + q];

    const size_t base = (size_t)seq * L_N + (size_t)blk * BLKSAMP;
    load_tile(x + base, xt, tid);
    __syncthreads();

    float t[8] = {0, 0, 0, 0, 0, 0, 0, 0};
    const float* xr = &xt[tid * ROWP];
    #pragma unroll 4
    for (int j = 0; j < CHUNK; ++j) (void)cascade_step(cf, t, xr[j]);

    // Kogge-Stone over 128 chunk maps.
    for (int l = 0; l < NLVL; ++l) {
        const int d = 1 << l;
        #pragma unroll
        for (int q = 0; q < 8; ++q) tb[tid][q] = t[q];
        __syncthreads();
        float prev[8];
        const bool have = (tid >= d);
        if (have) {
            #pragma unroll
            for (int q = 0; q < 8; ++q) prev[q] = tb[tid - d][q];
        }
        __syncthreads();
        if (have) {
            #pragma unroll
            for (int r = 0; r < 8; ++r) {
                float acc = t[r];
                #pragma unroll
                for (int c = 0; c < 8; ++c)
                    acc = fmaf(Pm[l][r * 8 + c], prev[c], acc);
                t[r] = acc;
            }
        }
    }

    // exclusive prefix -> compact coalesced region out[base + 8*tid ..)
    float e[8] = {0, 0, 0, 0, 0, 0, 0, 0};
    if (tid > 0) {
        #pragma unroll
        for (int q = 0; q < 8; ++q) e[q] = tb[tid - 1][q];
    }
    float4* eo = (float4*)(out + base);
    eo[2 * tid]     = make_float4(e[0], e[1], e[2], e[3]);
    eo[2 * tid + 1] = make_float4(e[4], e[5], e[6], e[7]);

    if (tid == THREADS - 1) {
        float* agg = (float*)ws + WS_AGG + (size_t)blockIdx.x * 8;
        #pragma unroll
        for (int q = 0; q < 8; ++q) agg[q] = t[q];
    }
}

// ---------------------------------------------------------------------------
// K3: inter-block scan. One wave; lane = sequence. Serial fold of 32 block
// aggregates with P = A^8192; converts AGG in place to exclusive prefixes.
// ---------------------------------------------------------------------------
__global__ __launch_bounds__(64) void svf_scanb(float* __restrict__ ws)
{
    const int seq = threadIdx.x;
    const int b   = seq >> 1;
    float P[64];
    #pragma unroll
    for (int q = 0; q < 64; ++q) P[q] = ws[WS_PBLK + b * 64 + q];

    float* agg = ws + WS_AGG + (size_t)seq * NBLK_SEQ * 8;

    float t[8] = {0, 0, 0, 0, 0, 0, 0, 0};
    for (int j = 0; j < NBLK_SEQ; ++j) {
        float f[8];
        #pragma unroll
        for (int q = 0; q < 8; ++q) f[q] = agg[j * 8 + q];
        #pragma unroll
        for (int q = 0; q < 8; ++q) agg[j * 8 + q] = t[q];   // exclusive
        float nt[8];
        #pragma unroll
        for (int r = 0; r < 8; ++r) {
            float acc = f[r];
            #pragma unroll
            for (int c = 0; c < 8; ++c) acc = fmaf(P[r * 8 + c], t[c], acc);
            nt[r] = acc;
        }
        #pragma unroll
        for (int q = 0; q < 8; ++q) t[q] = nt[q];
    }
}

// ---------------------------------------------------------------------------
// K4: final pass. s0 = stored excl prefix (coalesced read from out, before
// barrier) + A^(64*tid) * S_blk (commuting bit-decomp). Cascade on the
// LDS-staged tile, y written back into the tile, coalesced store.
// ---------------------------------------------------------------------------
__global__ __launch_bounds__(THREADS) void svf_pass2(
    const float* __restrict__ x, const float* __restrict__ ws,
    float* __restrict__ out)
{
    const int seq = blockIdx.x >> 5;
    const int blk = blockIdx.x & (NBLK_SEQ - 1);
    const int tid = threadIdx.x;
    const int b   = seq >> 1;

    __shared__ float xt[THREADS * ROWP];
    __shared__ float Pm[NLVL][64];

    for (int q = tid; q < NLVL * 64; q += THREADS)
        Pm[q >> 6][q & 63] = ws[WS_PL + b * NLVL * 64 + q];

    float cf[20];
    #pragma unroll
    for (int q = 0; q < 20; ++q) cf[q] = ws[WS_COEF + b * 20 + q];

    const size_t base = (size_t)seq * L_N + (size_t)blk * BLKSAMP;

    // own exclusive prefix (coalesced; written by pass1)
    const float4* eo = (const float4*)(out + base);
    float4 e0 = eo[2 * tid], e1 = eo[2 * tid + 1];

    // block initial state (uniform address -> broadcast)
    const float* sbp = ws + WS_AGG + (size_t)blockIdx.x * 8;
    float v[8];
    #pragma unroll
    for (int q = 0; q < 8; ++q) v[q] = sbp[q];

    load_tile(x + base, xt, tid);

    // v = A^(CHUNK*tid) * S_blk via commuting power-of-two factors
    __syncthreads();                          // Pm + tile ready; states read
    #pragma unroll
    for (int l = 0; l < NLVL; ++l) {
        if ((tid >> l) & 1) {
            float nv[8];
            #pragma unroll
            for (int r = 0; r < 8; ++r) {
                float acc = 0.0f;
                #pragma unroll
                for (int c = 0; c < 8; ++c)
                    acc = fmaf(Pm[l][r * 8 + c], v[c], acc);
                nv[r] = acc;
            }
            #pragma unroll
            for (int q = 0; q < 8; ++q) v[q] = nv[q];
        }
    }

    float s[8] = {e0.x + v[0], e0.y + v[1], e0.z + v[2], e0.w + v[3],
                  e1.x + v[4], e1.y + v[5], e1.z + v[6], e1.w + v[7]};

    float* xr = &xt[tid * ROWP];
    #pragma unroll 4
    for (int j = 0; j < CHUNK; ++j) xr[j] = cascade_step(cf, s, xr[j]);
    __syncthreads();

    // coalesced store of the y tile
    #pragma unroll
    for (int k = 0; k < BLKSAMP / 4 / THREADS; ++k) {
        const int g0 = (tid + k * THREADS) * 4;
        const int a = (g0 >> 6) * ROWP + (g0 & 63);
        ((float4*)(out + base))[tid + k * THREADS] =
            make_float4(xt[a], xt[a + 1], xt[a + 2], xt[a + 3]);
    }
}

// ---------------------------------------------------------------------------
extern "C" void kernel_launch(void* const* d_in, const int* in_sizes, int n_in,
                              void* d_out, int out_size, void* d_ws, size_t ws_size,
                              hipStream_t stream)
{
    (void)in_sizes; (void)n_in; (void)out_size; (void)ws_size;
    const float* x    = (const float*)d_in[0];
    const float* twoR = (const float*)d_in[1];
    const float* G    = (const float*)d_in[2];
    const float* chp  = (const float*)d_in[3];
    const float* cbp  = (const float*)d_in[4];
    const float* clp  = (const float*)d_in[5];
    float* out = (float*)d_out;
    float* ws  = (float*)d_ws;

    svf_prep <<<B_N, 64, 0, stream>>>(twoR, G, chp, cbp, clp, ws);
    svf_pass1<<<NBLK_TOT, THREADS, 0, stream>>>(x, ws, out);
    svf_scanb<<<1, 64, 0, stream>>>(ws);
    svf_pass2<<<NBLK_TOT, THREADS, 0, stream>>>(x, ws, out);
}

// Round 6
// 163.870 us; speedup vs baseline: 1.6367x; 1.0534x over previous
//
#include <hip/hip_runtime.h>
#include <math.h>

// Problem constants (from reference): B=32, C=2, L=262144, K=4
#define B_N 32
#define C_N 2
#define L_N 262144
#define K_N 4
#define NSEQ (B_N * C_N)            // 64 independent sequences
#define CHUNK 32                    // samples per thread (in registers)
#define THREADS 256                 // threads per pass block
#define BLKSAMP (CHUNK * THREADS)   // 8192 samples per block
#define NBLK_SEQ (L_N / BLKSAMP)    // 32 blocks per sequence
#define NBLK_TOT (NSEQ * NBLK_SEQ)  // 2048 pass blocks
#define NLVL 8                      // log2(THREADS): KS levels / bit-decomp bits
#define ROWW 33                     // window row stride (bank-conflict-free)

// d_ws float layout (35456 floats = 141.8 KB):
//   [coef : 32*20   =   640]
//   [PL   : 32*8*64 = 16384]  A^(32*2^l) = A^(2^(5+l)), l=0..7, per b
//   [PBLK : 32*64   =  2048]  A^8192 per b
//   [AGG  : 2048*8  = 16384]  block aggregates -> (scanb) block init states
#define WS_COEF 0
#define WS_PL   (B_N * 20)
#define WS_PBLK (WS_PL + B_N * NLVL * 64)
#define WS_AGG  (WS_PBLK + B_N * 64)

// ---------------------------------------------------------------------------
// K1: per-batch coefficient prep + transition-matrix powers (fp64).
// ---------------------------------------------------------------------------
__global__ __launch_bounds__(64) void svf_prep(
    const float* __restrict__ twoR, const float* __restrict__ Graw,
    const float* __restrict__ c_hp, const float* __restrict__ c_bp,
    const float* __restrict__ c_lp, float* __restrict__ ws)
{
    const int b = blockIdx.x;
    const int t = threadIdx.x;
    __shared__ double cf[K_N][5];   // b0,b1,b2,a1,a2 (normalized, a0==1)
    __shared__ double M[8][8];

    if (t < K_N) {
        const int k = t;
        double g  = (double)Graw[b * K_N + k];
        double tr = (double)twoR[b * K_N + k];
        double hp = (double)c_hp[b * K_N + k];
        double bp = (double)c_bp[b * K_N + k];
        double lp = (double)c_lp[b * K_N + k];
        double sg = 1.0 / (1.0 + exp(-g));
        double G  = tan(1.5707963267948966 * sg);
        double R  = log1p(exp(tr)) * 1.4426950408889634 + 0.01; // softplus/ln2 + .01
        double G2 = G * G;
        double b0 = hp + bp * G + lp * G2;
        double b1 = -2.0 * hp + 2.0 * lp * G2;
        double b2 = hp - bp * G + lp * G2;
        double a0 = 1.0 + G2 + R * G;
        double a1 = 2.0 * G2 - 2.0;
        double a2 = 1.0 + G2 - R * G;
        cf[k][0] = b0 / a0; cf[k][1] = b1 / a0; cf[k][2] = b2 / a0;
        cf[k][3] = a1 / a0; cf[k][4] = a2 / a0;
    }
    __syncthreads();

    if (t < 20) ws[WS_COEF + b * 20 + t] = (float)cf[t / 5][t % 5];

    // Build A columns: one cascade step from s = e_t, x = 0.
    if (t < 8) {
        double s[8];
        #pragma unroll
        for (int i = 0; i < 8; ++i) s[i] = (i == t) ? 1.0 : 0.0;
        double in = 0.0;
        #pragma unroll
        for (int k = 0; k < K_N; ++k) {
            double y   = cf[k][0] * in + s[2 * k];
            double s1n = cf[k][1] * in - cf[k][3] * y + s[2 * k + 1];
            double s2n = cf[k][2] * in - cf[k][4] * y;
            s[2 * k] = s1n; s[2 * k + 1] = s2n; in = y;
        }
        #pragma unroll
        for (int i = 0; i < 8; ++i) M[i][t] = s[i];
    }
    __syncthreads();

    // Repeated squaring: after p squarings M = A^(2^p).
    // Store A^(2^(5+l)) l=0..7 (KS scan + bit-decomp) and A^(2^13) (block map).
    const int i = t >> 3, j = t & 7;
    for (int p = 1; p <= 13; ++p) {
        double acc = 0.0;
        #pragma unroll
        for (int k = 0; k < 8; ++k) acc += M[i][k] * M[k][j];
        __syncthreads();
        M[i][j] = acc;
        __syncthreads();
        if (p >= 5 && p <= 12) ws[WS_PL + (b * NLVL + (p - 5)) * 64 + t] = (float)acc;
        if (p == 13)           ws[WS_PBLK + b * 64 + t] = (float)acc;
    }
}

// ---------------------------------------------------------------------------
// Fused 4-biquad cascade step (normalized coefficients). 20 VALU ops/sample.
// ---------------------------------------------------------------------------
__device__ __forceinline__ float cascade_step(const float cf[20], float s[8], float in)
{
    #pragma unroll
    for (int k = 0; k < K_N; ++k) {
        float y  = fmaf(cf[k * 5 + 0], in, s[2 * k]);
        float t1 = fmaf(cf[k * 5 + 1], in, s[2 * k + 1]);
        float n1 = fmaf(-cf[k * 5 + 3], y, t1);
        float n2 = fmaf(-cf[k * 5 + 4], y, cf[k * 5 + 2] * in);
        s[2 * k] = n1; s[2 * k + 1] = n2;
        in = y;
    }
    return in;
}

// Staged coalesced load: x[base..base+8192) -> xr[32] registers.
// All 8 float4 loads issued up-front (max memory-level parallelism); LDS
// window (64 rows x ROWW) reused across 4 rounds, one wave consumes per round.
__device__ __forceinline__ void stage_load(const float4* __restrict__ xg4,
                                           float* __restrict__ win,
                                           float* __restrict__ xr, int tid)
{
    float4 v4[8];
    #pragma unroll
    for (int j = 0; j < 8; ++j) v4[j] = xg4[tid + j * THREADS];
    const int myw = tid >> 6, lane = tid & 63;
    #pragma unroll
    for (int r = 0; r < 4; ++r) {
        #pragma unroll
        for (int h = 0; h < 2; ++h) {
            const int fw = tid + h * THREADS;          // float4 idx in window
            const int a  = (fw >> 3) * ROWW + (fw & 7) * 4;
            float4 v = v4[2 * r + h];
            win[a] = v.x; win[a + 1] = v.y; win[a + 2] = v.z; win[a + 3] = v.w;
        }
        __syncthreads();
        if (myw == r) {
            #pragma unroll
            for (int j = 0; j < CHUNK; ++j) xr[j] = win[lane * ROWW + j];
        }
        __syncthreads();
    }
}

// ---------------------------------------------------------------------------
// K2: zero-state pass + intra-block KS scan.
// Writes per-thread EXCLUSIVE prefix -> compact coalesced head of the block's
// own output range; block aggregate -> ws[AGG].
// ---------------------------------------------------------------------------
__global__ __launch_bounds__(THREADS) void svf_pass1(
    const float* __restrict__ x, const float* __restrict__ ws,
    float* __restrict__ out)
{
    const int seq = blockIdx.x >> 5;          // / NBLK_SEQ
    const int blk = blockIdx.x & (NBLK_SEQ - 1);
    const int tid = threadIdx.x;
    const int b   = seq >> 1;

    __shared__ float smem[THREADS * 9];       // window (2112f) ∪ tb (2304f)
    __shared__ float Pm[NLVL * 64];

    for (int q = tid; q < NLVL * 64; q += THREADS)
        Pm[q] = ws[WS_PL + b * NLVL * 64 + q];

    float cf[20];
    #pragma unroll
    for (int q = 0; q < 20; ++q) cf[q] = ws[WS_COEF + b * 20 + q];

    const size_t base = (size_t)seq * L_N + (size_t)blk * BLKSAMP;
    float xr[CHUNK];
    stage_load((const float4*)(x + base), smem, xr, tid);

    float t[8] = {0, 0, 0, 0, 0, 0, 0, 0};
    #pragma unroll
    for (int j = 0; j < CHUNK; ++j) (void)cascade_step(cf, t, xr[j]);

    // Kogge-Stone over 256 chunk maps (tb aliases the staging window; the
    // last stage_load barrier guarantees the window is dead here).
    for (int l = 0; l < NLVL; ++l) {
        const int d = 1 << l;
        #pragma unroll
        for (int q = 0; q < 8; ++q) smem[tid * 9 + q] = t[q];
        __syncthreads();
        float prev[8];
        const bool have = (tid >= d);
        if (have) {
            #pragma unroll
            for (int q = 0; q < 8; ++q) prev[q] = smem[(tid - d) * 9 + q];
        }
        __syncthreads();
        if (have) {
            #pragma unroll
            for (int r = 0; r < 8; ++r) {
                float acc = t[r];
                #pragma unroll
                for (int c = 0; c < 8; ++c)
                    acc = fmaf(Pm[l * 64 + r * 8 + c], prev[c], acc);
                t[r] = acc;
            }
        }
    }
    #pragma unroll
    for (int q = 0; q < 8; ++q) smem[tid * 9 + q] = t[q];
    __syncthreads();

    // exclusive prefix -> compact coalesced region out[base + 8*tid ..)
    float e[8] = {0, 0, 0, 0, 0, 0, 0, 0};
    if (tid > 0) {
        #pragma unroll
        for (int q = 0; q < 8; ++q) e[q] = smem[(tid - 1) * 9 + q];
    }
    float4* eo = (float4*)(out + base);
    eo[2 * tid]     = make_float4(e[0], e[1], e[2], e[3]);
    eo[2 * tid + 1] = make_float4(e[4], e[5], e[6], e[7]);

    if (tid == THREADS - 1) {
        float* agg = (float*)ws + WS_AGG + (size_t)blockIdx.x * 8;
        #pragma unroll
        for (int q = 0; q < 8; ++q) agg[q] = t[q];
    }
}

// ---------------------------------------------------------------------------
// K3: inter-block scan. One wave; lane = sequence. Serial fold of 32 block
// aggregates with P = A^8192; converts AGG in place to exclusive prefixes.
// ---------------------------------------------------------------------------
__global__ __launch_bounds__(64) void svf_scanb(float* __restrict__ ws)
{
    const int seq = threadIdx.x;
    const int b   = seq >> 1;
    float P[64];
    #pragma unroll
    for (int q = 0; q < 64; ++q) P[q] = ws[WS_PBLK + b * 64 + q];

    float* agg = ws + WS_AGG + (size_t)seq * NBLK_SEQ * 8;

    float t[8] = {0, 0, 0, 0, 0, 0, 0, 0};
    for (int j = 0; j < NBLK_SEQ; ++j) {
        float f[8];
        #pragma unroll
        for (int q = 0; q < 8; ++q) f[q] = agg[j * 8 + q];
        #pragma unroll
        for (int q = 0; q < 8; ++q) agg[j * 8 + q] = t[q];   // exclusive
        float nt[8];
        #pragma unroll
        for (int r = 0; r < 8; ++r) {
            float acc = f[r];
            #pragma unroll
            for (int c = 0; c < 8; ++c) acc = fmaf(P[r * 8 + c], t[c], acc);
            nt[r] = acc;
        }
        #pragma unroll
        for (int q = 0; q < 8; ++q) t[q] = nt[q];
    }
}

// ---------------------------------------------------------------------------
// K4: final pass. s0 = stored excl prefix (read before any barrier-ordered
// store) + A^(32*tid) * S_blk (commuting bit-decomp). Cascade in registers,
// staged coalesced store of y.
// ---------------------------------------------------------------------------
__global__ __launch_bounds__(THREADS) void svf_pass2(
    const float* __restrict__ x, const float* __restrict__ ws,
    float* __restrict__ out)
{
    const int seq = blockIdx.x >> 5;
    const int blk = blockIdx.x & (NBLK_SEQ - 1);
    const int tid = threadIdx.x;
    const int b   = seq >> 1;

    __shared__ float smem[THREADS * 9];       // staging window only
    __shared__ float Pm[NLVL * 64];

    const size_t base = (size_t)seq * L_N + (size_t)blk * BLKSAMP;

    // own exclusive prefix (coalesced; written by pass1) — issue first
    const float4* eo = (const float4*)(out + base);
    float4 e0 = eo[2 * tid], e1 = eo[2 * tid + 1];

    // block initial state (uniform address -> broadcast)
    const float* sbp = ws + WS_AGG + (size_t)blockIdx.x * 8;
    float v[8];
    #pragma unroll
    for (int q = 0; q < 8; ++q) v[q] = sbp[q];

    for (int q = tid; q < NLVL * 64; q += THREADS)
        Pm[q] = ws[WS_PL + b * NLVL * 64 + q];

    float cf[20];
    #pragma unroll
    for (int q = 0; q < 20; ++q) cf[q] = ws[WS_COEF + b * 20 + q];

    float xr[CHUNK];
    stage_load((const float4*)(x + base), smem, xr, tid);   // barriers inside

    // v = A^(CHUNK*tid) * S_blk via commuting power-of-two factors
    #pragma unroll
    for (int l = 0; l < NLVL; ++l) {
        if ((tid >> l) & 1) {
            float nv[8];
            #pragma unroll
            for (int r = 0; r < 8; ++r) {
                float acc = 0.0f;
                #pragma unroll
                for (int c = 0; c < 8; ++c)
                    acc = fmaf(Pm[l * 64 + r * 8 + c], v[c], acc);
                nv[r] = acc;
            }
            #pragma unroll
            for (int q = 0; q < 8; ++q) v[q] = nv[q];
        }
    }

    float s[8] = {e0.x + v[0], e0.y + v[1], e0.z + v[2], e0.w + v[3],
                  e1.x + v[4], e1.y + v[5], e1.z + v[6], e1.w + v[7]};

    #pragma unroll
    for (int j = 0; j < CHUNK; ++j) xr[j] = cascade_step(cf, s, xr[j]);

    // staged coalesced store: registers -> window -> global
    const int myw = tid >> 6, lane = tid & 63;
    float4* og4 = (float4*)(out + base);
    for (int r = 0; r < 4; ++r) {
        if (myw == r) {
            #pragma unroll
            for (int j = 0; j < CHUNK; ++j) smem[lane * ROWW + j] = xr[j];
        }
        __syncthreads();
        #pragma unroll
        for (int h = 0; h < 2; ++h) {
            const int fw = tid + h * THREADS;
            const int a  = (fw >> 3) * ROWW + (fw & 7) * 4;
            og4[r * 512 + fw] =
                make_float4(smem[a], smem[a + 1], smem[a + 2], smem[a + 3]);
        }
        __syncthreads();
    }
}

// ---------------------------------------------------------------------------
extern "C" void kernel_launch(void* const* d_in, const int* in_sizes, int n_in,
                              void* d_out, int out_size, void* d_ws, size_t ws_size,
                              hipStream_t stream)
{
    (void)in_sizes; (void)n_in; (void)out_size; (void)ws_size;
    const float* x    = (const float*)d_in[0];
    const float* twoR = (const float*)d_in[1];
    const float* G    = (const float*)d_in[2];
    const float* chp  = (const float*)d_in[3];
    const float* cbp  = (const float*)d_in[4];
    const float* clp  = (const float*)d_in[5];
    float* out = (float*)d_out;
    float* ws  = (float*)d_ws;

    svf_prep <<<B_N, 64, 0, stream>>>(twoR, G, chp, cbp, clp, ws);
    svf_pass1<<<NBLK_TOT, THREADS, 0, stream>>>(x, ws, out);
    svf_scanb<<<1, 64, 0, stream>>>(ws);
    svf_pass2<<<NBLK_TOT, THREADS, 0, stream>>>(x, ws, out);
}